// Round 3
// baseline (495.282 us; speedup 1.0000x reference)
//
#include <hip/hip_runtime.h>
#include <hip/hip_bf16.h>

// ---------------------------------------------------------------------------
// HoRA linear: out = x @ (base_w + (150*ifft2(sparse_spectrum)) @ A)^T + b
// M=8192, N=4096, K=4096.  bf16 MFMA GEMM with f32 accumulate.
// GEMM: 256x256 tile, BK=64, 8 waves, 4-window/K-tile schedule; per-region
// earliest-legal staging (distance 3-6 windows), counted vmcnt(6/6/6/4),
// XOR-swizzled LDS (both-sides), raw s_barrier + setprio.
// ---------------------------------------------------------------------------

#define OUTF 4096
#define INF  4096
#define NFREQ 10000
#define MDIM 8192
#define KT   (INF / 64)

typedef __attribute__((ext_vector_type(8))) short bf16x8;
typedef __attribute__((ext_vector_type(4))) float f32x4;

__device__ __forceinline__ unsigned int bf16pack2(float a, float b) {
    unsigned int ua = __builtin_bit_cast(unsigned int, a);
    unsigned int ub = __builtin_bit_cast(unsigned int, b);
    ua = (ua + 0x7fffu + ((ua >> 16) & 1u)) >> 16;          // RNE
    ub = (ub + 0x7fffu + ((ub >> 16) & 1u)) & 0xffff0000u;  // RNE, keep high
    return ua | ub;
}

__device__ __forceinline__ void async_copy16(const void* g, void* l) {
    __builtin_amdgcn_global_load_lds(
        (__attribute__((address_space(1))) void*)(g),
        (__attribute__((address_space(3))) void*)(l),
        16, 0, 0);
}

// ---------------------------------------------------------------------------
// Kernel 1: B[o][r] = (150/16384) * sum_{nnz in chunk} val * cos(2*pi*phase)
// 1024 blocks x 256 thr: block = 64 outputs, 4 threads/output (nnz quarters).
// Deterministic ballot-prefix compaction by wave 0 (no atomics).
// ---------------------------------------------------------------------------
__global__ __launch_bounds__(256) void build_B_kernel(
        const float* __restrict__ spectrum, const int* __restrict__ idx,
        float* __restrict__ Bout) {
    __shared__ int2  s_jkv[3072];
    __shared__ float s_part[4][64];
    __shared__ int   s_cnt;
    const int tid  = threadIdx.x;
    const int gid0 = blockIdx.x * 64;      // first of 64 outputs
    const int p    = gid0 >> 14;           // chunk 0..3 (64 | 16384)

    if (tid < 64) {                        // wave 0: deterministic compaction
        int base = 0;
        for (int i0 = 0; i0 < NFREQ; i0 += 64) {
            const int i = i0 + tid;
            bool m = false; int id = 0;
            if (i < NFREQ) { id = idx[i]; m = ((id >> 14) == p); }
            unsigned long long bal = __ballot(m);
            if (m) {
                int pos = base + __popcll(bal & ((1ull << tid) - 1ull));
                if (pos < 3072)
                    s_jkv[pos] = make_int2(id & 16383,
                                           __builtin_bit_cast(int, spectrum[i]));
            }
            base += __popcll(bal);
        }
        if (tid == 0) s_cnt = (base < 3072) ? base : 3072;
    }
    __syncthreads();
    const int cnt  = s_cnt;
    const int qtr  = tid >> 6;             // nnz quarter 0..3
    const int ol   = tid & 63;             // output within block
    const int gid  = gid0 + ol;
    const int o    = gid >> 4;
    const int r    = gid & 15;
    const int m    = o & 1023;
    const int qlen = (cnt + 3) >> 2;
    const int t0   = qtr * qlen;
    const int t1   = (t0 + qlen < cnt) ? t0 + qlen : cnt;
    const float c  = 6.283185307179586f / 16384.f;
    float acc = 0.f;
    for (int t = t0; t < t1; ++t) {
        const int2 jv = s_jkv[t];
        const int j = jv.x >> 4, k = jv.x & 15;
        int ph = (((j * m) & 1023) << 4) + (((k * r) & 15) << 10);
        ph &= 16383;
        acc += __builtin_bit_cast(float, jv.y) * __cosf((float)ph * c);
    }
    s_part[qtr][ol] = acc;
    __syncthreads();
    if (tid < 64) {
        float s = s_part[0][tid] + s_part[1][tid] + s_part[2][tid] + s_part[3][tid];
        Bout[gid0 + tid] = s * (150.f / 16384.f);
    }
}

// ---------------------------------------------------------------------------
// Kernel 2: W_bf16[n][k] = bf16(base_w[n][k] + sum_r Bs[n][r] * A[r][k])
// ---------------------------------------------------------------------------
__global__ __launch_bounds__(256) void build_w_kernel(
        const float* __restrict__ bw, const float* __restrict__ A,
        const float* __restrict__ Bs, unsigned short* __restrict__ W) {
    const int n0 = blockIdx.x * 8;
    __shared__ float sB[8][16];
    if (threadIdx.x < 128)
        ((float*)sB)[threadIdx.x] = Bs[n0 * 16 + threadIdx.x];
    __syncthreads();
    const float4* A4 = (const float4*)A;
    const float4* bw4 = (const float4*)bw;
    uint2* W2 = (uint2*)W;
#pragma unroll 1
    for (int q = 0; q < 4; ++q) {
        const int c4 = threadIdx.x + q * 256;
        float4 a[16];
#pragma unroll
        for (int r = 0; r < 16; ++r) a[r] = A4[r * 1024 + c4];
#pragma unroll 1
        for (int nn = 0; nn < 8; ++nn) {
            const int n = n0 + nn;
            float4 wv = bw4[n * 1024 + c4];
#pragma unroll
            for (int r = 0; r < 16; ++r) {
                float s = sB[nn][r];
                wv.x += s * a[r].x; wv.y += s * a[r].y;
                wv.z += s * a[r].z; wv.w += s * a[r].w;
            }
            W2[n * 1024 + c4] = make_uint2(bf16pack2(wv.x, wv.y),
                                           bf16pack2(wv.z, wv.w));
        }
    }
}

// ---------------------------------------------------------------------------
// Kernel 3: x (f32) -> bf16
// ---------------------------------------------------------------------------
__global__ __launch_bounds__(256) void cvt_x_kernel(
        const float4* __restrict__ x, uint2* __restrict__ xb, int n4) {
    for (int i = blockIdx.x * blockDim.x + threadIdx.x; i < n4;
         i += gridDim.x * blockDim.x) {
        float4 v = x[i];
        xb[i] = make_uint2(bf16pack2(v.x, v.y), bf16pack2(v.z, v.w));
    }
}

// ---------------------------------------------------------------------------
// Kernel 4: 256x256-tile 8-wave deep-pipelined bf16 GEMM.
// Region lifetimes per tile (all waves): A0/A1 read thru window q2,
// B0/B1 read thru q1.  Stages at earliest-legal windows:
//   q0: A0(s+1)->OTH   q1: A1(s+1)->OTH   q2: B0(s+2)->CUR   q3: B1(s+2)->CUR
// vmcnt: q0/q1/q2 = 6, q3 = 4 (drains both A-halves of s+1 before q0(s+1)).
// bfa fragments for tile s+1 prefetched in window q3 (B(s+1) drained q1/q2).
// ---------------------------------------------------------------------------
__global__ __launch_bounds__(512, 2) void gemm256_kernel(
        const unsigned short* __restrict__ Xb,
        const unsigned short* __restrict__ Wb,
        const float* __restrict__ bias, float* __restrict__ C) {
    __shared__ __align__(1024) char lds[131072];

    const int tid  = threadIdx.x;
    const int lane = tid & 63;
    const int wid  = tid >> 6;
    const int wm   = wid >> 2;   // 0..1
    const int wn   = wid & 3;    // 0..3

    // XCD-bijective swizzle: nwg=512, divisible by 8.
    int bid = blockIdx.x;
    bid = (bid & 7) * 64 + (bid >> 3);
    const int tm = bid >> 4;     // 0..31  M tile
    const int tn = bid & 15;     // 0..15  N tile
    const int arow0 = tm * 256;
    const int brow0 = tn * 256;

    // staging: thread covers rows srow, srow+64 of a 128-row half, 16B chunk.
    const int srow  = tid >> 3;
    const int scole = (((tid & 7) * 16) ^ ((srow & 7) << 4)) >> 1;
    const int sldsb = tid * 16;

    // fragment reads: row = base + (lane&15); swizzle uses lane&7.
    const int l15 = lane & 15;
    const int kx0 = ((lane >> 4) * 16) ^ ((lane & 7) << 4);
    const int kx1 = kx0 ^ 64;
    const int abase0 = (wm * 128 + l15) * 128;
    const int bbase0 = 32768 + (wn * 64 + l15) * 128;

    f32x4 acc[8][4] = {};
    bf16x8 af[4][2], bfa[2][2], bfb[2][2];

#define STAGE_HALF(mat, grow0, t, ldsbase) do {                               \
        const unsigned short* _s =                                            \
            (mat) + ((grow0) + srow) * INF + (t) * 64 + scole;                \
        async_copy16(_s, lds + (ldsbase) + sldsb);                            \
        async_copy16(_s + 64 * INF, lds + (ldsbase) + 8192 + sldsb);          \
    } while (0)

#define LDA(DB, m, kh) (*(const bf16x8*)(lds + (DB) + abase0 + (m) * 2048 + ((kh) ? kx1 : kx0)))
#define LDB(DB, n, kh) (*(const bf16x8*)(lds + (DB) + bbase0 + (n) * 2048 + ((kh) ? kx1 : kx0)))
#define MFMA(a, b, c) __builtin_amdgcn_mfma_f32_16x16x32_bf16((a), (b), (c), 0, 0, 0)
#define BARRIER() do { asm volatile("" ::: "memory");                         \
                       __builtin_amdgcn_s_barrier();                          \
                       asm volatile("" ::: "memory"); } while (0)

#define TILE(CUR, OTH, s) do {                                                \
    /* ---- q0: read af(m0); stage A0(s+1)->OTH; MFMA acc[0..3][0..1] ---- */ \
    _Pragma("unroll") for (int m = 0; m < 4; ++m) {                           \
        af[m][0] = LDA(CUR, m, 0); af[m][1] = LDA(CUR, m, 1); }               \
    if ((s) + 1 < KT) STAGE_HALF(Xb, arow0, (s) + 1, (OTH) + 0);              \
    asm volatile("s_waitcnt vmcnt(6)" ::: "memory");                          \
    BARRIER();                                                                \
    asm volatile("s_waitcnt lgkmcnt(0)" ::: "memory");                        \
    __builtin_amdgcn_s_setprio(1);                                            \
    _Pragma("unroll") for (int m = 0; m < 4; ++m)                             \
        _Pragma("unroll") for (int n = 0; n < 2; ++n) {                       \
            acc[m][n] = MFMA(af[m][0], bfa[n][0], acc[m][n]);                 \
            acc[m][n] = MFMA(af[m][1], bfa[n][1], acc[m][n]); }               \
    __builtin_amdgcn_s_setprio(0);                                            \
    BARRIER();                                                                \
    /* ---- q1: read bfb; stage A1(s+1)->OTH; MFMA acc[0..3][2..3] ---- */    \
    _Pragma("unroll") for (int n = 0; n < 2; ++n) {                           \
        bfb[n][0] = LDB(CUR, n + 2, 0); bfb[n][1] = LDB(CUR, n + 2, 1); }     \
    if ((s) + 1 < KT) STAGE_HALF(Xb, arow0 + 128, (s) + 1, (OTH) + 16384);    \
    asm volatile("s_waitcnt vmcnt(6)" ::: "memory");                          \
    BARRIER();                                                                \
    asm volatile("s_waitcnt lgkmcnt(0)" ::: "memory");                        \
    __builtin_amdgcn_s_setprio(1);                                            \
    _Pragma("unroll") for (int m = 0; m < 4; ++m)                             \
        _Pragma("unroll") for (int n = 0; n < 2; ++n) {                       \
            acc[m][n + 2] = MFMA(af[m][0], bfb[n][0], acc[m][n + 2]);         \
            acc[m][n + 2] = MFMA(af[m][1], bfb[n][1], acc[m][n + 2]); }       \
    __builtin_amdgcn_s_setprio(0);                                            \
    BARRIER();                                                                \
    /* ---- q2: read af(m1); stage B0(s+2)->CUR; MFMA acc[4..7][0..1] ---- */ \
    _Pragma("unroll") for (int m = 0; m < 4; ++m) {                           \
        af[m][0] = LDA(CUR, m + 4, 0); af[m][1] = LDA(CUR, m + 4, 1); }       \
    if ((s) + 2 < KT) STAGE_HALF(Wb, brow0, (s) + 2, (CUR) + 32768);          \
    if ((s) < KT - 2) { asm volatile("s_waitcnt vmcnt(6)" ::: "memory"); }    \
    else              { asm volatile("s_waitcnt vmcnt(4)" ::: "memory"); }    \
    BARRIER();                                                                \
    asm volatile("s_waitcnt lgkmcnt(0)" ::: "memory");                        \
    __builtin_amdgcn_s_setprio(1);                                            \
    _Pragma("unroll") for (int m = 0; m < 4; ++m)                             \
        _Pragma("unroll") for (int n = 0; n < 2; ++n) {                       \
            acc[m + 4][n] = MFMA(af[m][0], bfa[n][0], acc[m + 4][n]);         \
            acc[m + 4][n] = MFMA(af[m][1], bfa[n][1], acc[m + 4][n]); }       \
    __builtin_amdgcn_s_setprio(0);                                            \
    BARRIER();                                                                \
    /* ---- q3: prefetch bfa(s+1) from OTH; stage B1(s+2)->CUR;          */   \
    /* ---- MFMA acc[4..7][2..3]                                         */   \
    if ((s) + 1 < KT) {                                                       \
        _Pragma("unroll") for (int n = 0; n < 2; ++n) {                       \
            bfa[n][0] = LDB(OTH, n, 0); bfa[n][1] = LDB(OTH, n, 1); }         \
    }                                                                         \
    if ((s) + 2 < KT) STAGE_HALF(Wb, brow0 + 128, (s) + 2, (CUR) + 49152);    \
    if ((s) < KT - 2) { asm volatile("s_waitcnt vmcnt(4)" ::: "memory"); }    \
    else              { asm volatile("s_waitcnt vmcnt(0)" ::: "memory"); }    \
    BARRIER();                                                                \
    asm volatile("s_waitcnt lgkmcnt(4)" ::: "memory");                        \
    __builtin_amdgcn_s_setprio(1);                                            \
    _Pragma("unroll") for (int m = 0; m < 4; ++m)                             \
        _Pragma("unroll") for (int n = 0; n < 2; ++n) {                       \
            acc[m + 4][n + 2] = MFMA(af[m][0], bfb[n][0], acc[m + 4][n + 2]); \
            acc[m + 4][n + 2] = MFMA(af[m][1], bfb[n][1], acc[m + 4][n + 2]); \
        }                                                                     \
    __builtin_amdgcn_s_setprio(0);                                            \
    BARRIER();                                                                \
} while (0)

    // ---- prologue: tile0 fully -> buf0, B0/B1(t1) -> buf1 ----
    STAGE_HALF(Xb, arow0,       0, 0);
    STAGE_HALF(Xb, arow0 + 128, 0, 16384);
    STAGE_HALF(Wb, brow0,       0, 32768);
    STAGE_HALF(Wb, brow0 + 128, 0, 49152);
    STAGE_HALF(Wb, brow0,       1, 65536 + 32768);
    STAGE_HALF(Wb, brow0 + 128, 1, 65536 + 49152);
    asm volatile("s_waitcnt vmcnt(4)" ::: "memory");
    BARRIER();
#pragma unroll
    for (int n = 0; n < 2; ++n) {          // initial bfa from buf0
        bfa[n][0] = LDB(0, n, 0); bfa[n][1] = LDB(0, n, 1);
    }

    for (int s = 0; s < KT; s += 2) {
        TILE(0, 65536, s);
        TILE(65536, 0, s + 1);
    }

    // ---- epilogue: C = acc + bias ----
#pragma unroll
    for (int n = 0; n < 4; ++n) {
        const int gcol = brow0 + wn * 64 + n * 16 + l15;
        const float bv = bias[gcol];
#pragma unroll
        for (int m = 0; m < 8; ++m) {
            const int grow = arow0 + wm * 128 + m * 16 + (lane >> 4) * 4;
#pragma unroll
            for (int rg = 0; rg < 4; ++rg)
                C[(grow + rg) * OUTF + gcol] = acc[m][n][rg] + bv;
        }
    }
#undef STAGE_HALF
#undef LDA
#undef LDB
#undef MFMA
#undef BARRIER
#undef TILE
}

// ---------------------------------------------------------------------------
extern "C" void kernel_launch(void* const* d_in, const int* in_sizes, int n_in,
                              void* d_out, int out_size, void* d_ws, size_t ws_size,
                              hipStream_t stream) {
    const float* x    = (const float*)d_in[0];   // [4,2048,4096]
    const float* bw   = (const float*)d_in[1];   // [4096,4096]
    const float* bb   = (const float*)d_in[2];   // [4096]
    const float* spec = (const float*)d_in[3];   // [10000]
    const float* ha   = (const float*)d_in[4];   // [16,4096]
    const int*   idx  = (const int*)d_in[5];     // [10000]
    float* out = (float*)d_out;

    char* ws = (char*)d_ws;
    float*          Bbuf = (float*)ws;                                // 256 KB
    unsigned short* Wb   = (unsigned short*)(ws + 262144);            // 32 MB
    unsigned short* Xb   = (unsigned short*)(ws + 262144 + 33554432); // 64 MB

    build_B_kernel<<<1024, 256, 0, stream>>>(spec, idx, Bbuf);
    build_w_kernel<<<512, 256, 0, stream>>>(bw, ha, Bbuf, Wb);
    cvt_x_kernel<<<2048, 256, 0, stream>>>((const float4*)x, (uint2*)Xb,
                                           (MDIM * INF) / 4);
    gemm256_kernel<<<512, 512, 0, stream>>>(Xb, Wb, bb, out);
}

// Round 5
// 466.233 us; speedup vs baseline: 1.0623x; 1.0623x over previous
//
#include <hip/hip_runtime.h>
#include <hip/hip_bf16.h>

// ---------------------------------------------------------------------------
// HoRA linear: out = x @ (base_w + (150*ifft2(sparse_spectrum)) @ A)^T + b
// M=8192, N=4096, K=4096.  bf16 MFMA GEMM with f32 accumulate.
// GEMM: 256x256 tile, BK=64, 8 waves, 32x32x16 MFMA, 2 windows/K-tile,
// 4 barriers + 1 vmcnt per K-tile, XOR-swizzled LDS (both-sides).
// Race fix vs r4: B(s+2) stage moved AFTER the W1 barrier (all waves'
// B-reads drained); A(s+1)/B(s+1) retired by vmcnt(4) at END of W1 so the
// closing barrier doubles as the RAW fence for tile s+1's ds_reads.
// ---------------------------------------------------------------------------

#define OUTF 4096
#define INF  4096
#define NFREQ 10000
#define MDIM 8192
#define KT   (INF / 64)

typedef __attribute__((ext_vector_type(8)))  short bf16x8;
typedef __attribute__((ext_vector_type(16))) float f32x16;

__device__ __forceinline__ unsigned int bf16pack2(float a, float b) {
    unsigned int ua = __builtin_bit_cast(unsigned int, a);
    unsigned int ub = __builtin_bit_cast(unsigned int, b);
    ua = (ua + 0x7fffu + ((ua >> 16) & 1u)) >> 16;          // RNE
    ub = (ub + 0x7fffu + ((ub >> 16) & 1u)) & 0xffff0000u;  // RNE, keep high
    return ua | ub;
}

__device__ __forceinline__ void async_copy16(const void* g, void* l) {
    __builtin_amdgcn_global_load_lds(
        (__attribute__((address_space(1))) void*)(g),
        (__attribute__((address_space(3))) void*)(l),
        16, 0, 0);
}

// ---------------------------------------------------------------------------
// Kernel 1a: compact nnz per chunk (4 blocks, deterministic ballot prefix).
// ---------------------------------------------------------------------------
__global__ __launch_bounds__(256) void compact_kernel(
        const float* __restrict__ spectrum, const int* __restrict__ idx,
        int2* __restrict__ cjk, int* __restrict__ ccnt) {
    const int p   = blockIdx.x;          // chunk 0..3
    const int tid = threadIdx.x;
    const int wv  = tid >> 6, ln = tid & 63;
    __shared__ int wcnt[4];
    int cnt = 0;
    for (int i0 = wv * 64; i0 < NFREQ; i0 += 256) {
        const int i = i0 + ln;
        bool m = (i < NFREQ) && ((idx[i] >> 14) == p);
        cnt += __popcll(__ballot(m));
    }
    if (ln == 0) wcnt[wv] = cnt;
    __syncthreads();
    int base = 0;
    for (int w = 0; w < wv; ++w) base += wcnt[w];
    for (int i0 = wv * 64; i0 < NFREQ; i0 += 256) {
        const int i = i0 + ln;
        bool m = false; int id = 0;
        if (i < NFREQ) { id = idx[i]; m = ((id >> 14) == p); }
        unsigned long long bal = __ballot(m);
        if (m) {
            int pos = base + __popcll(bal & ((1ull << ln) - 1ull));
            if (pos < 4096)
                cjk[p * 4096 + pos] =
                    make_int2(id & 16383, __builtin_bit_cast(int, spectrum[i]));
        }
        base += __popcll(bal);
    }
    if (tid == 0) {
        int t = wcnt[0] + wcnt[1] + wcnt[2] + wcnt[3];
        ccnt[p] = (t < 4096) ? t : 4096;
    }
}

// ---------------------------------------------------------------------------
// Kernel 1b: B[o][r] = (150/16384) * sum_nnz val * cos(2*pi*phase/16384)
// 1024 blocks x 256 thr: 64 outputs/block, 4 threads/output.
// ---------------------------------------------------------------------------
__global__ __launch_bounds__(256) void buildB_kernel(
        const int2* __restrict__ cjk, const int* __restrict__ ccnt,
        float* __restrict__ Bout) {
    __shared__ int2  s_jkv[4096];
    __shared__ float s_part[4][64];
    const int tid  = threadIdx.x;
    const int gid0 = blockIdx.x * 64;
    const int p    = gid0 >> 14;
    const int cnt  = ccnt[p];
    for (int t = tid; t < cnt; t += 256) s_jkv[t] = cjk[p * 4096 + t];
    __syncthreads();
    const int qtr  = tid >> 6;
    const int ol   = tid & 63;
    const int gid  = gid0 + ol;
    const int o    = gid >> 4;
    const int r    = gid & 15;
    const int m    = o & 1023;
    const int qlen = (cnt + 3) >> 2;
    const int t0   = qtr * qlen;
    const int t1   = (t0 + qlen < cnt) ? t0 + qlen : cnt;
    const float c  = 6.283185307179586f / 16384.f;
    float acc = 0.f;
    for (int t = t0; t < t1; ++t) {
        const int2 jv = s_jkv[t];
        const int j = jv.x >> 4, k = jv.x & 15;
        int ph = (((j * m) & 1023) << 4) + (((k * r) & 15) << 10);
        acc += __builtin_bit_cast(float, jv.y) * __cosf((float)(ph & 16383) * c);
    }
    s_part[qtr][ol] = acc;
    __syncthreads();
    if (tid < 64) {
        float s = s_part[0][tid] + s_part[1][tid] + s_part[2][tid] + s_part[3][tid];
        Bout[gid0 + tid] = s * (150.f / 16384.f);
    }
}

// ---------------------------------------------------------------------------
// Kernel 2: W_bf16[n][k] = bf16(base_w[n][k] + sum_r Bs[n][r] * A[r][k])
// ---------------------------------------------------------------------------
__global__ __launch_bounds__(256) void build_w_kernel(
        const float* __restrict__ bw, const float* __restrict__ A,
        const float* __restrict__ Bs, unsigned short* __restrict__ W) {
    const int n0 = blockIdx.x * 8;
    __shared__ float sB[8][16];
    if (threadIdx.x < 128)
        ((float*)sB)[threadIdx.x] = Bs[n0 * 16 + threadIdx.x];
    __syncthreads();
    const float4* A4 = (const float4*)A;
    const float4* bw4 = (const float4*)bw;
    uint2* W2 = (uint2*)W;
#pragma unroll 1
    for (int q = 0; q < 4; ++q) {
        const int c4 = threadIdx.x + q * 256;
        float4 a[16];
#pragma unroll
        for (int r = 0; r < 16; ++r) a[r] = A4[r * 1024 + c4];
#pragma unroll 1
        for (int nn = 0; nn < 8; ++nn) {
            const int n = n0 + nn;
            float4 wv = bw4[n * 1024 + c4];
#pragma unroll
            for (int r = 0; r < 16; ++r) {
                float s = sB[nn][r];
                wv.x += s * a[r].x; wv.y += s * a[r].y;
                wv.z += s * a[r].z; wv.w += s * a[r].w;
            }
            W2[n * 1024 + c4] = make_uint2(bf16pack2(wv.x, wv.y),
                                           bf16pack2(wv.z, wv.w));
        }
    }
}

// ---------------------------------------------------------------------------
// Kernel 3: x (f32) -> bf16
// ---------------------------------------------------------------------------
__global__ __launch_bounds__(256) void cvt_x_kernel(
        const float4* __restrict__ x, uint2* __restrict__ xb, int n4) {
    for (int i = blockIdx.x * blockDim.x + threadIdx.x; i < n4;
         i += gridDim.x * blockDim.x) {
        float4 v = x[i];
        xb[i] = make_uint2(bf16pack2(v.x, v.y), bf16pack2(v.z, v.w));
    }
}

// ---------------------------------------------------------------------------
// Kernel 4: 256x256-tile 8-wave bf16 GEMM, mfma_f32_32x32x16_bf16.
// Hazard ledger (issue order ... B(s+1)[W1(s-1)] A(s+1)[W0(s)] B(s+2)[W1(s)]):
//  - W0(s) reads A(s),B(s): retired by vmcnt(4) at end of W1(s-1) + barrier.
//  - W0(s) stage A(s+1)->OTH: OTH A-region reads ended before W1(s-1)'s
//    first barrier (per-wave lgkmcnt(0)); two barriers intervene. Safe.
//  - W1(s) stage B(s+2)->CUR: issued AFTER the W1 barrier that follows all
//    waves' lgkmcnt(0) -> no wave still reading CUR B-region. Safe.
//  - end W1(s): vmcnt(4) retires B(s+1),A(s+1) (leaves B(s+2)); closing
//    barrier makes them visible to all waves' tile-s+1 ds_reads.
// ---------------------------------------------------------------------------
__global__ __launch_bounds__(512, 2) void gemm256_kernel(
        const unsigned short* __restrict__ Xb,
        const unsigned short* __restrict__ Wb,
        const float* __restrict__ bias, float* __restrict__ C) {
    __shared__ __align__(1024) char lds[131072];

    const int tid  = threadIdx.x;
    const int lane = tid & 63;
    const int wid  = tid >> 6;
    const int wm   = wid >> 2;   // 0..1
    const int wn   = wid & 3;    // 0..3

    // XCD-bijective swizzle: nwg=512, divisible by 8.
    int bid = blockIdx.x;
    bid = (bid & 7) * 64 + (bid >> 3);
    const int tm = bid >> 4;     // 0..31  M tile
    const int tn = bid & 15;     // 0..15  N tile
    const int arow0 = tm * 256;
    const int brow0 = tn * 256;

    // staging: thread covers rows srow, srow+64 of a 128-row half, 16B chunk.
    const int srow  = tid >> 3;
    const int scole = (((tid & 7) * 16) ^ ((srow & 7) << 4)) >> 1;
    const int sldsb = tid * 16;

    // fragment reads (32x32x16): row = base + (lane&31); 8 bf16 at
    // k = (lane>>5)*8 + [0,8) of k-step ks; byte = (ks<<5) ^ kxr.
    const int l31 = lane & 31;
    const int kxr = ((lane >> 5) << 4) ^ ((lane & 7) << 4);
    const int abase = (wm * 128 + l31) * 128;            // + f*32*128
    const int bbase = 32768 + (wn * 64 + l31) * 128;     // + n*32*128

    f32x16 acc[4][2] = {};
    bf16x8 af[4][2], bf[2][2];

#define STAGE_HALF(mat, grow0, t, ldsbase) do {                               \
        const unsigned short* _s =                                            \
            (mat) + ((grow0) + srow) * INF + (t) * 64 + scole;                \
        async_copy16(_s, lds + (ldsbase) + sldsb);                            \
        async_copy16(_s + 64 * INF, lds + (ldsbase) + 8192 + sldsb);          \
    } while (0)

#define LDA(DB, f, ks) (*(const bf16x8*)(lds + (DB) + abase + (f) * 4096 + (((ks) << 5) ^ kxr)))
#define LDB(DB, n, ks) (*(const bf16x8*)(lds + (DB) + bbase + (n) * 4096 + (((ks) << 5) ^ kxr)))
#define MFMA(a, b, c) __builtin_amdgcn_mfma_f32_32x32x16_bf16((a), (b), (c), 0, 0, 0)
#define BARRIER() do { asm volatile("" ::: "memory");                         \
                       __builtin_amdgcn_s_barrier();                          \
                       asm volatile("" ::: "memory"); } while (0)

#define TILE(CUR, OTH, s) do {                                                \
    /* ---- W0: k-steps 0,1 from CUR; stage A(s+1)->OTH ---- */               \
    _Pragma("unroll") for (int f = 0; f < 4; ++f) {                           \
        af[f][0] = LDA(CUR, f, 0); af[f][1] = LDA(CUR, f, 1); }               \
    _Pragma("unroll") for (int n = 0; n < 2; ++n) {                           \
        bf[n][0] = LDB(CUR, n, 0); bf[n][1] = LDB(CUR, n, 1); }               \
    if ((s) + 1 < KT) {                                                       \
        STAGE_HALF(Xb, arow0,       (s) + 1, (OTH) + 0);                      \
        STAGE_HALF(Xb, arow0 + 128, (s) + 1, (OTH) + 16384);                  \
    }                                                                         \
    asm volatile("s_waitcnt lgkmcnt(0)" ::: "memory");                        \
    BARRIER();                                                                \
    __builtin_amdgcn_s_setprio(1);                                            \
    _Pragma("unroll") for (int ks = 0; ks < 2; ++ks)                          \
        _Pragma("unroll") for (int f = 0; f < 4; ++f)                         \
            _Pragma("unroll") for (int n = 0; n < 2; ++n)                     \
                acc[f][n] = MFMA(af[f][ks], bf[n][ks], acc[f][n]);            \
    __builtin_amdgcn_s_setprio(0);                                            \
    BARRIER();                                                                \
    /* ---- W1: k-steps 2,3; barrier; THEN stage B(s+2)->CUR ---- */          \
    _Pragma("unroll") for (int f = 0; f < 4; ++f) {                           \
        af[f][0] = LDA(CUR, f, 2); af[f][1] = LDA(CUR, f, 3); }               \
    _Pragma("unroll") for (int n = 0; n < 2; ++n) {                           \
        bf[n][0] = LDB(CUR, n, 2); bf[n][1] = LDB(CUR, n, 3); }               \
    asm volatile("s_waitcnt lgkmcnt(0)" ::: "memory");                        \
    BARRIER();                                                                \
    if ((s) + 2 < KT) {                                                       \
        STAGE_HALF(Wb, brow0,       (s) + 2, (CUR) + 32768);                  \
        STAGE_HALF(Wb, brow0 + 128, (s) + 2, (CUR) + 49152);                  \
    }                                                                         \
    __builtin_amdgcn_s_setprio(1);                                            \
    _Pragma("unroll") for (int ks = 0; ks < 2; ++ks)                          \
        _Pragma("unroll") for (int f = 0; f < 4; ++f)                         \
            _Pragma("unroll") for (int n = 0; n < 2; ++n)                     \
                acc[f][n] = MFMA(af[f][ks], bf[n][ks], acc[f][n]);            \
    __builtin_amdgcn_s_setprio(0);                                            \
    if ((s) + 2 < KT) { asm volatile("s_waitcnt vmcnt(4)" ::: "memory"); }    \
    else              { asm volatile("s_waitcnt vmcnt(0)" ::: "memory"); }    \
    BARRIER();                                                                \
} while (0)

    // ---- prologue: A(0),B(0)->buf0, B(1)->buf1; retire A(0),B(0) ----
    STAGE_HALF(Xb, arow0,       0, 0);
    STAGE_HALF(Xb, arow0 + 128, 0, 16384);
    STAGE_HALF(Wb, brow0,       0, 32768);
    STAGE_HALF(Wb, brow0 + 128, 0, 49152);
    STAGE_HALF(Wb, brow0,       1, 65536 + 32768);
    STAGE_HALF(Wb, brow0 + 128, 1, 65536 + 49152);
    asm volatile("s_waitcnt vmcnt(4)" ::: "memory");
    BARRIER();

    for (int s = 0; s < KT; s += 2) {
        TILE(0, 65536, s);
        TILE(65536, 0, s + 1);
    }

    // ---- epilogue: C = acc + bias ----
    // 32x32 C layout: col = lane&31, row = (reg&3) + 8*(reg>>2) + 4*(lane>>5)
#pragma unroll
    for (int n = 0; n < 2; ++n) {
        const int gcol = brow0 + wn * 64 + n * 32 + l31;
        const float bv = bias[gcol];
#pragma unroll
        for (int f = 0; f < 4; ++f) {
            const int rbase = arow0 + wm * 128 + f * 32 + 4 * (lane >> 5);
#pragma unroll
            for (int reg = 0; reg < 16; ++reg) {
                const int grow = rbase + (reg & 3) + 8 * (reg >> 2);
                C[grow * OUTF + gcol] = acc[f][n][reg] + bv;
            }
        }
    }
#undef STAGE_HALF
#undef LDA
#undef LDB
#undef MFMA
#undef BARRIER
#undef TILE
}

// ---------------------------------------------------------------------------
extern "C" void kernel_launch(void* const* d_in, const int* in_sizes, int n_in,
                              void* d_out, int out_size, void* d_ws, size_t ws_size,
                              hipStream_t stream) {
    const float* x    = (const float*)d_in[0];   // [4,2048,4096]
    const float* bw   = (const float*)d_in[1];   // [4096,4096]
    const float* bb   = (const float*)d_in[2];   // [4096]
    const float* spec = (const float*)d_in[3];   // [10000]
    const float* ha   = (const float*)d_in[4];   // [16,4096]
    const int*   idx  = (const int*)d_in[5];     // [10000]
    float* out = (float*)d_out;

    char* ws = (char*)d_ws;
    float*          Bbuf = (float*)ws;                                // 256 KB
    unsigned short* Wb   = (unsigned short*)(ws + 262144);            // 32 MB
    unsigned short* Xb   = (unsigned short*)(ws + 262144 + 33554432); // 64 MB
    int2*           cjk  = (int2*)(ws + 262144 + 33554432 + 67108864);// 128 KB
    int*            ccnt = (int*)(ws + 262144 + 33554432 + 67108864 + 131072);

    compact_kernel<<<4, 256, 0, stream>>>(spec, idx, cjk, ccnt);
    buildB_kernel<<<1024, 256, 0, stream>>>(cjk, ccnt, Bbuf);
    build_w_kernel<<<512, 256, 0, stream>>>(bw, ha, Bbuf, Wb);
    cvt_x_kernel<<<2048, 256, 0, stream>>>((const float4*)x, (uint2*)Xb,
                                           (MDIM * INF) / 4);
    gemm256_kernel<<<512, 512, 0, stream>>>(Xb, Wb, bb, out);
}